// Round 2
// baseline (1764.739 us; speedup 1.0000x reference)
//
#include <hip/hip_runtime.h>
#include <math.h>

// Problem dims (fixed by setup_inputs)
#define BB   8
#define NN   2304          // 48*48
#define CIN  512           // hidden*2
#define HID  256
#define QKV3 768           // hidden*3
#define MM   (BB * NN)     // 18432
#define SCALE 0.125f       // 1/sqrt(64)

// ---------------------------------------------------------------------------
// C[M][Ndim] = A[M][Kdim] @ W[Kdim][Ndim] + bias   (fp32, 128x128 tile, BK=16)
// 256 threads, each computes 8x8 micro-tile.
// ---------------------------------------------------------------------------
__global__ __launch_bounds__(256) void gemm_bias(
    const float* __restrict__ A, const float* __restrict__ W,
    const float* __restrict__ bias, float* __restrict__ C,
    int Kdim, int Ndim)
{
    __shared__ float As[16][132];   // A tile transposed: As[k][m], padded
    __shared__ float Bs[16][128];   // B tile: Bs[k][n]

    const int t  = threadIdx.x;
    const int m0 = blockIdx.y * 128;
    const int n0 = blockIdx.x * 128;

    // global-load mapping
    const int lm = t >> 1;          // 0..127  (A row)
    const int lk = (t & 1) * 8;     // 0 or 8  (A k-chunk)
    const int wk = t >> 4;          // 0..15   (W row)
    const int wn = (t & 15) * 8;    // 0..120  (W col chunk)
    // compute mapping
    const int rbase = (t >> 4) * 8; // 0..120
    const int cbase = (t & 15) * 8; // 0..120

    float acc[8][8];
#pragma unroll
    for (int i = 0; i < 8; ++i)
#pragma unroll
        for (int j = 0; j < 8; ++j) acc[i][j] = 0.f;

    for (int kt = 0; kt < Kdim; kt += 16) {
        // stage into registers first
        const float4 a0 = *(const float4*)&A[(m0 + lm) * Kdim + kt + lk];
        const float4 a1 = *(const float4*)&A[(m0 + lm) * Kdim + kt + lk + 4];
        const float4 b0 = *(const float4*)&W[(wk + kt) * Ndim + n0 + wn];
        const float4 b1 = *(const float4*)&W[(wk + kt) * Ndim + n0 + wn + 4];
        __syncthreads();   // previous iteration's LDS reads done
        As[lk + 0][lm] = a0.x; As[lk + 1][lm] = a0.y;
        As[lk + 2][lm] = a0.z; As[lk + 3][lm] = a0.w;
        As[lk + 4][lm] = a1.x; As[lk + 5][lm] = a1.y;
        As[lk + 6][lm] = a1.z; As[lk + 7][lm] = a1.w;
        *(float4*)&Bs[wk][wn]     = b0;
        *(float4*)&Bs[wk][wn + 4] = b1;
        __syncthreads();

#pragma unroll
        for (int k = 0; k < 16; ++k) {
            const float4 aa0 = *(const float4*)&As[k][rbase];
            const float4 aa1 = *(const float4*)&As[k][rbase + 4];
            const float4 bb0 = *(const float4*)&Bs[k][cbase];
            const float4 bb1 = *(const float4*)&Bs[k][cbase + 4];
            const float av[8] = {aa0.x, aa0.y, aa0.z, aa0.w, aa1.x, aa1.y, aa1.z, aa1.w};
            const float bv[8] = {bb0.x, bb0.y, bb0.z, bb0.w, bb1.x, bb1.y, bb1.z, bb1.w};
#pragma unroll
            for (int i = 0; i < 8; ++i)
#pragma unroll
                for (int j = 0; j < 8; ++j)
                    acc[i][j] = fmaf(av[i], bv[j], acc[i][j]);
        }
    }

    // epilogue: add bias, store
    const float4 bv0 = *(const float4*)&bias[n0 + cbase];
    const float4 bv1 = *(const float4*)&bias[n0 + cbase + 4];
#pragma unroll
    for (int i = 0; i < 8; ++i) {
        const int row = m0 + rbase + i;
        float4 o0, o1;
        o0.x = acc[i][0] + bv0.x; o0.y = acc[i][1] + bv0.y;
        o0.z = acc[i][2] + bv0.z; o0.w = acc[i][3] + bv0.w;
        o1.x = acc[i][4] + bv1.x; o1.y = acc[i][5] + bv1.y;
        o1.z = acc[i][6] + bv1.z; o1.w = acc[i][7] + bv1.w;
        *(float4*)&C[row * Ndim + n0 + cbase]     = o0;
        *(float4*)&C[row * Ndim + n0 + cbase + 4] = o1;
    }
}

// ---------------------------------------------------------------------------
// Flash attention (fp32): one block handles 32 query rows of one batch.
// qkv rows are [q(256) | k(256) | v(256)]. V streamed from global (L2-hot).
// KBLK=32, 2x2 S micro-tile, b128 LDS reads both operands.
// ---------------------------------------------------------------------------
#define QBLK 32
#define KBLK 32
#define QPAD 260   // 32 rows -> banks r*4: conflict-free across row groups

__global__ __launch_bounds__(256) void attn_kernel(
    const float* __restrict__ qkv, float* __restrict__ attno)
{
    __shared__ float Qs[QBLK][QPAD];       // 33.3 KB, pre-scaled by SCALE
    __shared__ float Ks[KBLK][QPAD];       // 33.3 KB, row-major K tile
    __shared__ float Sp[QBLK][KBLK + 1];   // 4.2 KB, scores -> probabilities
    __shared__ float m_sh[QBLK], l_sh[QBLK], f_sh[QBLK];

    const int t    = threadIdx.x;
    const int b    = blockIdx.y;
    const int q0   = blockIdx.x * QBLK;    // row offset within batch
    const int base = b * NN;               // global row base of this batch

    // ---- load Q tile (scaled) ----
    {
        const int r  = t >> 3;             // 0..31
        const int d0 = (t & 7) * 32;       // 0..224
        const float* src = &qkv[(base + q0 + r) * QKV3 + d0];
#pragma unroll
        for (int j = 0; j < 32; j += 4) {
            float4 v = *(const float4*)&src[j];
            v.x *= SCALE; v.y *= SCALE; v.z *= SCALE; v.w *= SCALE;
            *(float4*)&Qs[r][d0 + j] = v;
        }
    }
    if (t < QBLK) { m_sh[t] = -1e30f; l_sh[t] = 0.f; }

    // PV accumulator mapping: thread owns 8 rows x 4 cols
    const int pr = (t >> 6) * 8;           // wave w -> rows 8w..8w+7
    const int pd = (t & 63) * 4;           // 0..252
    float o[8][4];
#pragma unroll
    for (int i = 0; i < 8; ++i)
#pragma unroll
        for (int j = 0; j < 4; ++j) o[i][j] = 0.f;

    // S mapping: thread computes 2 rows x 2 cols
    const int sc = (t & 15) * 2;           // cols sc, sc+1
    const int sr = (t >> 4) * 2;           // rows sr, sr+1
    const int koff = (t & 4) ? 4 : 0;      // k-rotation: 4-way -> 2-way banks
    // softmax mapping: 8 lanes per row, 4 cols each
    const int mr = t >> 3;                 // 0..31
    const int mj = (t & 7) * 4;            // 0..28

    __syncthreads();

    for (int kt = 0; kt < NN; kt += KBLK) {
        // ---- load K tile row-major: Ks[c][k] = K[kt+c][k] ----
        {
            const int c  = t >> 3;         // 0..31 (key row within tile)
            const int k0 = (t & 7) * 32;   // 0..224
            const float* src = &qkv[(base + kt + c) * QKV3 + 256 + k0];
#pragma unroll
            for (int j = 0; j < 32; j += 4)
                *(float4*)&Ks[c][k0 + j] = *(const float4*)&src[j];
        }
        __syncthreads();

        // ---- S = (Q*scale) @ K^T : 32x32, 2x2 per thread ----
        {
            float s00 = 0.f, s01 = 0.f, s10 = 0.f, s11 = 0.f;
#pragma unroll 4
            for (int k = 0; k < 256; k += 4) {
                const int kk = (k + koff) & 255;
                const float4 qa = *(const float4*)&Qs[sr][kk];
                const float4 qb = *(const float4*)&Qs[sr + 1][kk];
                const float4 ka = *(const float4*)&Ks[sc][kk];
                const float4 kb = *(const float4*)&Ks[sc + 1][kk];
                s00 = fmaf(qa.x, ka.x, s00); s00 = fmaf(qa.y, ka.y, s00);
                s00 = fmaf(qa.z, ka.z, s00); s00 = fmaf(qa.w, ka.w, s00);
                s01 = fmaf(qa.x, kb.x, s01); s01 = fmaf(qa.y, kb.y, s01);
                s01 = fmaf(qa.z, kb.z, s01); s01 = fmaf(qa.w, kb.w, s01);
                s10 = fmaf(qb.x, ka.x, s10); s10 = fmaf(qb.y, ka.y, s10);
                s10 = fmaf(qb.z, ka.z, s10); s10 = fmaf(qb.w, ka.w, s10);
                s11 = fmaf(qb.x, kb.x, s11); s11 = fmaf(qb.y, kb.y, s11);
                s11 = fmaf(qb.z, kb.z, s11); s11 = fmaf(qb.w, kb.w, s11);
            }
            Sp[sr][sc]         = s00;
            Sp[sr][sc + 1]     = s01;
            Sp[sr + 1][sc]     = s10;
            Sp[sr + 1][sc + 1] = s11;
        }
        __syncthreads();

        // ---- online softmax update (8 lanes per row, 4 cols each) ----
        {
            const float s0 = Sp[mr][mj];
            const float s1 = Sp[mr][mj + 1];
            const float s2 = Sp[mr][mj + 2];
            const float s3 = Sp[mr][mj + 3];
            float pmax = fmaxf(fmaxf(s0, s1), fmaxf(s2, s3));
            pmax = fmaxf(pmax, __shfl_xor(pmax, 1));
            pmax = fmaxf(pmax, __shfl_xor(pmax, 2));
            pmax = fmaxf(pmax, __shfl_xor(pmax, 4));
            const float mold = m_sh[mr];
            const float mnew = fmaxf(mold, pmax);
            const float f    = __expf(mold - mnew);
            const float p0   = __expf(s0 - mnew);
            const float p1   = __expf(s1 - mnew);
            const float p2   = __expf(s2 - mnew);
            const float p3   = __expf(s3 - mnew);
            float ps = (p0 + p1) + (p2 + p3);
            ps += __shfl_xor(ps, 1);
            ps += __shfl_xor(ps, 2);
            ps += __shfl_xor(ps, 4);
            // all 8 lanes of the row group hold identical values: benign dup writes
            l_sh[mr] = l_sh[mr] * f + ps;
            m_sh[mr] = mnew;
            f_sh[mr] = f;
            Sp[mr][mj]     = p0;
            Sp[mr][mj + 1] = p1;
            Sp[mr][mj + 2] = p2;
            Sp[mr][mj + 3] = p3;
        }
        __syncthreads();

        // ---- PV: o = o*f + P @ V (V streamed from global, L2-hot) ----
        {
#pragma unroll
            for (int i = 0; i < 8; ++i) {
                const float f = f_sh[pr + i];
                o[i][0] *= f; o[i][1] *= f; o[i][2] *= f; o[i][3] *= f;
            }
#pragma unroll 4
            for (int c = 0; c < KBLK; ++c) {
                const float4 v = *(const float4*)&qkv[(base + kt + c) * QKV3 + 512 + pd];
#pragma unroll
                for (int i = 0; i < 8; ++i) {
                    const float p = Sp[pr + i][c];
                    o[i][0] = fmaf(p, v.x, o[i][0]);
                    o[i][1] = fmaf(p, v.y, o[i][1]);
                    o[i][2] = fmaf(p, v.z, o[i][2]);
                    o[i][3] = fmaf(p, v.w, o[i][3]);
                }
            }
        }
        __syncthreads();   // Sp/Ks reuse next tile
    }

    // ---- finalize: divide by l, store ----
#pragma unroll
    for (int i = 0; i < 8; ++i) {
        const float inv = 1.f / l_sh[pr + i];
        float4 v;
        v.x = o[i][0] * inv; v.y = o[i][1] * inv;
        v.z = o[i][2] * inv; v.w = o[i][3] * inv;
        *(float4*)&attno[(base + q0 + pr + i) * HID + pd] = v;
    }
}

// ---------------------------------------------------------------------------
extern "C" void kernel_launch(void* const* d_in, const int* in_sizes, int n_in,
                              void* d_out, int out_size, void* d_ws, size_t ws_size,
                              hipStream_t stream)
{
    (void)in_sizes; (void)n_in; (void)out_size; (void)ws_size;
    const float* x  = (const float*)d_in[0];
    const float* W1 = (const float*)d_in[1];
    const float* b1 = (const float*)d_in[2];
    const float* W2 = (const float*)d_in[3];
    const float* b2 = (const float*)d_in[4];
    float* out = (float*)d_out;

    float* qkv   = (float*)d_ws;                 // MM*768 f32 = 56.6 MB
    float* attno = qkv + (size_t)MM * QKV3;      // MM*256 f32 = 18.9 MB

    // 1) qkv = x @ W1 + b1
    gemm_bias<<<dim3(QKV3 / 128, MM / 128), 256, 0, stream>>>(x, W1, b1, qkv, CIN, QKV3);
    // 2) flash attention
    attn_kernel<<<dim3(NN / QBLK, BB), 256, 0, stream>>>(qkv, attno);
    // 3) out = attno @ W2 + b2
    gemm_bias<<<dim3(HID / 128, MM / 128), 256, 0, stream>>>(attno, W2, b2, out, HID, HID);
}

// Round 3
// 555.275 us; speedup vs baseline: 3.1781x; 3.1781x over previous
//
#include <hip/hip_runtime.h>
#include <math.h>

typedef _Float16 f16;
typedef __attribute__((ext_vector_type(8))) _Float16 f16x8;
typedef __attribute__((ext_vector_type(4))) _Float16 f16x4;
typedef __attribute__((ext_vector_type(4))) float f32x4;

#define BB   8
#define NN   2304
#define CIN  512
#define HID  256
#define QKV3 768
#define MM   (BB * NN)
#define SCALE 0.125f

#define MFMA16(a, b, c) __builtin_amdgcn_mfma_f32_16x16x32_f16(a, b, c, 0, 0, 0)

// ---------------------------------------------------------------------------
// Transpose + f32->f16: Wt[n][k] = (f16)W[k][n]
// ---------------------------------------------------------------------------
__global__ __launch_bounds__(256) void transpose_f32_to_f16(
    const float* __restrict__ W, f16* __restrict__ Wt, int K, int N)
{
    __shared__ float tile[32][33];
    const int tx = threadIdx.x & 31, ty = threadIdx.x >> 5;
    const int n0 = blockIdx.x * 32, k0 = blockIdx.y * 32;
#pragma unroll
    for (int i = 0; i < 4; ++i)
        tile[ty + i * 8][tx] = W[(long)(k0 + ty + i * 8) * N + n0 + tx];
    __syncthreads();
#pragma unroll
    for (int i = 0; i < 4; ++i)
        Wt[(long)(n0 + ty + i * 8) * K + k0 + tx] = (f16)tile[tx][ty + i * 8];
}

// ---------------------------------------------------------------------------
// MFMA GEMM: C = A @ Bt^T + bias.  Bt is [Ndim][Kdim] f16 (pre-transposed W).
// Tile 128x128, BK=64, 256 threads, 4 waves (2x2), 64x64 per wave.
// VAR 0: A = f32, C = f16 (qkv; scale cols<256 by 0.125 after bias)
// VAR 1: A = f16, C = f32
// ---------------------------------------------------------------------------
template <int VAR>
__global__ __launch_bounds__(256) void gemm_mfma(
    const void* __restrict__ Ap, const f16* __restrict__ Bt,
    const float* __restrict__ bias, void* __restrict__ Cp,
    int Kdim, int Ndim, int NB)
{
    __shared__ char lds[32768];
    char* As = lds;           // [128][64] f16, byte = row*128 + (col2 ^ ((row&7)<<4))
    char* Bs = lds + 16384;

    const int t = threadIdx.x;
    const int lane = t & 63;
    const int w = t >> 6;
    const int chunk = gridDim.x >> 3;                      // gridDim.x % 8 == 0
    const int bsw = (blockIdx.x & 7) * chunk + (blockIdx.x >> 3);
    const int m0 = (bsw / NB) * 128;
    const int n0 = (bsw % NB) * 128;
    const int wm = (w >> 1) * 64;
    const int wn = (w & 1) * 64;
    const int NK = Kdim >> 6;

    f32x4 acc[4][4];
#pragma unroll
    for (int i = 0; i < 4; ++i)
#pragma unroll
        for (int j = 0; j < 4; ++j) acc[i][j] = (f32x4){0.f, 0.f, 0.f, 0.f};

    float4 a32[8];
    int4   a16[4];
    int4   breg[4];

    auto loadA = [&](int kt) {
        if (VAR == 0) {
            const float* A = (const float*)Ap;
#pragma unroll
            for (int i = 0; i < 8; ++i) {
                const int cid = t + i * 256, row = cid >> 4, cir = cid & 15;
                a32[i] = *(const float4*)&A[(long)(m0 + row) * Kdim + kt * 64 + cir * 4];
            }
        } else {
            const f16* A = (const f16*)Ap;
#pragma unroll
            for (int i = 0; i < 4; ++i) {
                const int cid = t + i * 256, row = cid >> 3, cir = cid & 7;
                a16[i] = *(const int4*)&A[(long)(m0 + row) * Kdim + kt * 64 + cir * 8];
            }
        }
#pragma unroll
        for (int i = 0; i < 4; ++i) {
            const int cid = t + i * 256, row = cid >> 3, cir = cid & 7;
            breg[i] = *(const int4*)&Bt[(long)(n0 + row) * Kdim + kt * 64 + cir * 8];
        }
    };
    auto writeLDS = [&]() {
        if (VAR == 0) {
#pragma unroll
            for (int i = 0; i < 8; ++i) {
                const int cid = t + i * 256, row = cid >> 4, cir = cid & 15;
                f16x4 v = {(f16)a32[i].x, (f16)a32[i].y, (f16)a32[i].z, (f16)a32[i].w};
                *(f16x4*)(As + row * 128 + ((cir * 8) ^ ((row & 7) << 4))) = v;
            }
        } else {
#pragma unroll
            for (int i = 0; i < 4; ++i) {
                const int cid = t + i * 256, row = cid >> 3, cir = cid & 7;
                *(int4*)(As + row * 128 + ((cir * 16) ^ ((row & 7) << 4))) = a16[i];
            }
        }
#pragma unroll
        for (int i = 0; i < 4; ++i) {
            const int cid = t + i * 256, row = cid >> 3, cir = cid & 7;
            *(int4*)(Bs + row * 128 + ((cir * 16) ^ ((row & 7) << 4))) = breg[i];
        }
    };

    loadA(0);
    writeLDS();
    __syncthreads();

    for (int kt = 0; kt < NK; ++kt) {
        if (kt + 1 < NK) loadA(kt + 1);
#pragma unroll
        for (int ks = 0; ks < 2; ++ks) {
            f16x8 af[4], bf[4];
            const int kb = (ks * 32 + ((lane >> 4) * 8)) * 2;
#pragma unroll
            for (int mb = 0; mb < 4; ++mb) {
                const int row = wm + mb * 16 + (lane & 15);
                af[mb] = *(const f16x8*)(As + row * 128 + (kb ^ ((row & 7) << 4)));
            }
#pragma unroll
            for (int nb = 0; nb < 4; ++nb) {
                const int row = wn + nb * 16 + (lane & 15);
                bf[nb] = *(const f16x8*)(Bs + row * 128 + (kb ^ ((row & 7) << 4)));
            }
#pragma unroll
            for (int mb = 0; mb < 4; ++mb)
#pragma unroll
                for (int nb = 0; nb < 4; ++nb)
                    acc[mb][nb] = MFMA16(af[mb], bf[nb], acc[mb][nb]);
        }
        __syncthreads();
        if (kt + 1 < NK) { writeLDS(); __syncthreads(); }
    }

#pragma unroll
    for (int nb = 0; nb < 4; ++nb) {
        const int col = n0 + wn + nb * 16 + (lane & 15);
        const float bv = bias[col];
        const float sc = (VAR == 0 && col < HID) ? SCALE : 1.0f;
#pragma unroll
        for (int mb = 0; mb < 4; ++mb)
#pragma unroll
            for (int j = 0; j < 4; ++j) {
                const int row = m0 + wm + mb * 16 + (lane >> 4) * 4 + j;
                const float v = (acc[mb][nb][j] + bv) * sc;
                if (VAR == 0) ((f16*)Cp)[(long)row * Ndim + col] = (f16)v;
                else          ((float*)Cp)[(long)row * Ndim + col] = v;
            }
    }
}

// ---------------------------------------------------------------------------
// Flash attention, f16 MFMA. qkv rows: [q*0.125 (256) | k (256) | v (256)] f16.
// Block: 256 thr (4 waves), QM=64 q-rows (16/wave), KT=64 kv per tile.
// K LDS [64][256] swz ^((r&15)<<4); V LDS transposed [256][64] swz ^((r&7)<<4);
// P per-wave [16][64] swz ^((r&7)<<4). Grid 288 1-D, batch = bid%8 (XCD-L2).
// ---------------------------------------------------------------------------
#define QM 64
#define KT 64

__global__ __launch_bounds__(256) void attn_mfma(
    const f16* __restrict__ qkv, f16* __restrict__ attno)
{
    __shared__ char lds[73728];
    char* Ks = lds;            // 32 KB
    char* Vt = lds + 32768;    // 32 KB
    char* Pw = lds + 65536;    // 8 KB (4 waves x 2 KB)

    const int t = threadIdx.x;
    const int lane = t & 63;
    const int w = t >> 6;
    const int b = blockIdx.x & 7;
    const int q0 = (blockIdx.x >> 3) * QM;
    const long base = (long)b * NN;

    // Q fragments (A operand) held in registers for the whole kernel
    const int qrow = q0 + w * 16 + (lane & 15);
    f16x8 qf[8];
    {
        const f16* qsrc = qkv + (base + qrow) * QKV3 + ((lane >> 4) * 8);
#pragma unroll
        for (int ks = 0; ks < 8; ++ks)
            qf[ks] = *(const f16x8*)(qsrc + ks * 32);
    }

    f32x4 o[16];
#pragma unroll
    for (int i = 0; i < 16; ++i) o[i] = (f32x4){0.f, 0.f, 0.f, 0.f};
    float m[4], lsum[4];
#pragma unroll
    for (int j = 0; j < 4; ++j) { m[j] = -1e30f; lsum[j] = 0.f; }

    const int vdg = (t >> 4) * 16;   // d-group base (16 d per thread)
    const int vquad = t & 15;        // kv quad (4 kv rows per thread)

    for (int kt0 = 0; kt0 < NN; kt0 += KT) {
        // ---- K tile: global f16 -> regs (coalesced 16B/lane) ----
        int4 kreg[8];
#pragma unroll
        for (int i = 0; i < 8; ++i) {
            const int cid = t + i * 256, row = cid >> 5, cir = cid & 31;
            kreg[i] = *(const int4*)(qkv + (base + kt0 + row) * QKV3 + 256 + cir * 8);
        }
        __syncthreads();   // previous tile's LDS reads complete
#pragma unroll
        for (int i = 0; i < 8; ++i) {
            const int cid = t + i * 256, row = cid >> 5, cir = cid & 31;
            *(int4*)(Ks + row * 512 + ((cir * 16) ^ ((row & 15) << 4))) = kreg[i];
        }
        // ---- V tile: load 4 kv rows x 16 d, write transposed ----
        f16x8 vreg[8];
#pragma unroll
        for (int r = 0; r < 4; ++r) {
            const f16* vs = qkv + (base + kt0 + vquad * 4 + r) * QKV3 + 512 + vdg;
            vreg[r * 2]     = *(const f16x8*)(vs);
            vreg[r * 2 + 1] = *(const f16x8*)(vs + 8);
        }
#pragma unroll
        for (int i = 0; i < 16; ++i) {
            const int d = vdg + i;
            f16x4 wv;
#pragma unroll
            for (int r = 0; r < 4; ++r)
                wv[r] = (i < 8) ? vreg[r * 2][i] : vreg[r * 2 + 1][i - 8];
            *(f16x4*)(Vt + d * 128 + ((vquad * 8) ^ ((d & 7) << 4))) = wv;
        }
        __syncthreads();   // staging complete

        // ---- S = Q @ K^T (wave's 16 rows x 64 kv) ----
        f32x4 s[4];
#pragma unroll
        for (int nb = 0; nb < 4; ++nb) s[nb] = (f32x4){0.f, 0.f, 0.f, 0.f};
#pragma unroll
        for (int ks = 0; ks < 8; ++ks) {
            const int kb = (ks * 32 + (lane >> 4) * 8) * 2;
#pragma unroll
            for (int nb = 0; nb < 4; ++nb) {
                const int row = nb * 16 + (lane & 15);
                f16x8 kf = *(const f16x8*)(Ks + row * 512 + (kb ^ ((row & 15) << 4)));
                s[nb] = MFMA16(qf[ks], kf, s[nb]);
            }
        }

        // ---- online softmax (rows live in 16-lane groups; reg j = row%4) ----
        float f[4];
#pragma unroll
        for (int j = 0; j < 4; ++j) {
            float rmax = fmaxf(fmaxf(s[0][j], s[1][j]), fmaxf(s[2][j], s[3][j]));
            rmax = fmaxf(rmax, __shfl_xor(rmax, 1));
            rmax = fmaxf(rmax, __shfl_xor(rmax, 2));
            rmax = fmaxf(rmax, __shfl_xor(rmax, 4));
            rmax = fmaxf(rmax, __shfl_xor(rmax, 8));
            const float mnew = fmaxf(m[j], rmax);
            f[j] = __expf(m[j] - mnew);
            const float p0 = __expf(s[0][j] - mnew);
            const float p1 = __expf(s[1][j] - mnew);
            const float p2 = __expf(s[2][j] - mnew);
            const float p3 = __expf(s[3][j] - mnew);
            float ps = (p0 + p1) + (p2 + p3);
            ps += __shfl_xor(ps, 1);
            ps += __shfl_xor(ps, 2);
            ps += __shfl_xor(ps, 4);
            ps += __shfl_xor(ps, 8);
            lsum[j] = lsum[j] * f[j] + ps;
            m[j] = mnew;
            // write P row (f16) to per-wave LDS, swizzled
            const int prow = (lane >> 4) * 4 + j;
            char* pr = Pw + w * 2048 + prow * 128;
            const int cb = (lane & 15) * 2;
            const int sw = (prow & 7) << 4;
            *(f16*)(pr + ((cb +  0) ^ sw)) = (f16)p0;
            *(f16*)(pr + ((cb + 32) ^ sw)) = (f16)p1;
            *(f16*)(pr + ((cb + 64) ^ sw)) = (f16)p2;
            *(f16*)(pr + ((cb + 96) ^ sw)) = (f16)p3;
        }
        // rescale accumulator by f (per row-reg j)
#pragma unroll
        for (int nb2 = 0; nb2 < 16; ++nb2)
#pragma unroll
            for (int j = 0; j < 4; ++j) o[nb2][j] *= f[j];

        asm volatile("s_waitcnt lgkmcnt(0)" ::: "memory");
        __builtin_amdgcn_sched_barrier(0);

        // ---- O += P @ V ----
#pragma unroll
        for (int ks2 = 0; ks2 < 2; ++ks2) {
            const int prow = lane & 15;
            const int kb = (ks2 * 32 + (lane >> 4) * 8) * 2;
            f16x8 pa = *(const f16x8*)(Pw + w * 2048 + prow * 128 + (kb ^ ((prow & 7) << 4)));
#pragma unroll
            for (int nb2 = 0; nb2 < 16; ++nb2) {
                const int d = nb2 * 16 + (lane & 15);
                f16x8 vb = *(const f16x8*)(Vt + d * 128 + (kb ^ ((d & 7) << 4)));
                o[nb2] = MFMA16(pa, vb, o[nb2]);
            }
        }
    }

    // ---- finalize: /l, store f16 ----
    float rinv[4];
#pragma unroll
    for (int j = 0; j < 4; ++j) rinv[j] = 1.f / lsum[j];
#pragma unroll
    for (int nb2 = 0; nb2 < 16; ++nb2) {
        const int col = nb2 * 16 + (lane & 15);
#pragma unroll
        for (int j = 0; j < 4; ++j) {
            const int row = q0 + w * 16 + (lane >> 4) * 4 + j;
            attno[(base + row) * HID + col] = (f16)(o[nb2][j] * rinv[j]);
        }
    }
}

// ---------------------------------------------------------------------------
extern "C" void kernel_launch(void* const* d_in, const int* in_sizes, int n_in,
                              void* d_out, int out_size, void* d_ws, size_t ws_size,
                              hipStream_t stream)
{
    (void)in_sizes; (void)n_in; (void)out_size; (void)ws_size;
    const float* x  = (const float*)d_in[0];
    const float* W1 = (const float*)d_in[1];
    const float* b1 = (const float*)d_in[2];
    const float* W2 = (const float*)d_in[3];
    const float* b2 = (const float*)d_in[4];
    float* out = (float*)d_out;

    char* ws = (char*)d_ws;
    f16* W1t   = (f16*)ws;                               // 768*512  f16 = 768 KB
    f16* W2t   = (f16*)(ws + 786432);                    // 256*256  f16 = 128 KB
    f16* qkv   = (f16*)(ws + 786432 + 131072);           // 18432*768 f16 = 27 MB
    f16* attno = (f16*)(ws + 786432 + 131072 + 28311552);// 18432*256 f16 = 9 MB

    transpose_f32_to_f16<<<dim3(QKV3 / 32, CIN / 32), 256, 0, stream>>>(W1, W1t, CIN, QKV3);
    transpose_f32_to_f16<<<dim3(HID / 32, HID / 32), 256, 0, stream>>>(W2, W2t, HID, HID);
    // qkv = x @ W1 + b1 (f16 out, q pre-scaled)
    gemm_mfma<0><<<864, 256, 0, stream>>>(x, W1t, b1, qkv, CIN, QKV3, 6);
    // flash attention
    attn_mfma<<<288, 256, 0, stream>>>(qkv, attno);
    // out = attno @ W2 + b2 (f32 out)
    gemm_mfma<1><<<288, 256, 0, stream>>>(attno, W2t, b2, out, HID, HID, 2);
}

// Round 10
// 513.806 us; speedup vs baseline: 3.4346x; 1.0807x over previous
//
#include <hip/hip_runtime.h>
#include <math.h>

typedef _Float16 f16;
typedef __attribute__((ext_vector_type(8))) _Float16 f16x8;
typedef __attribute__((ext_vector_type(4))) _Float16 f16x4;
typedef __attribute__((ext_vector_type(4))) float f32x4;

#define BB   8
#define NN   2304
#define CIN  512
#define HID  256
#define QKV3 768
#define MM   (BB * NN)
#define SCALE 0.125f

#define MFMA16(a, b, c) __builtin_amdgcn_mfma_f32_16x16x32_f16(a, b, c, 0, 0, 0)

// ---------------------------------------------------------------------------
// Transpose + f32->f16: Wt[n][k] = (f16)W[k][n]
// ---------------------------------------------------------------------------
__global__ __launch_bounds__(256) void transpose_f32_to_f16(
    const float* __restrict__ W, f16* __restrict__ Wt, int K, int N)
{
    __shared__ float tile[32][33];
    const int tx = threadIdx.x & 31, ty = threadIdx.x >> 5;
    const int n0 = blockIdx.x * 32, k0 = blockIdx.y * 32;
#pragma unroll
    for (int i = 0; i < 4; ++i)
        tile[ty + i * 8][tx] = W[(long)(k0 + ty + i * 8) * N + n0 + tx];
    __syncthreads();
#pragma unroll
    for (int i = 0; i < 4; ++i)
        Wt[(long)(n0 + ty + i * 8) * K + k0 + tx] = (f16)tile[tx][ty + i * 8];
}

// ---------------------------------------------------------------------------
// MFMA GEMM: C = A @ Bt^T + bias.  Bt is [Ndim][Kdim] f16 (pre-transposed W).
// Tile 128x128, BK=64, 256 threads, 4 waves (2x2), 64x64 per wave.
// VAR 0: A = f32, C = f16 (qkv; scale cols<256 by 0.125 after bias)
// VAR 1: A = f16, C = f32
// ---------------------------------------------------------------------------
template <int VAR>
__global__ __launch_bounds__(256) void gemm_mfma(
    const void* __restrict__ Ap, const f16* __restrict__ Bt,
    const float* __restrict__ bias, void* __restrict__ Cp,
    int Kdim, int Ndim, int NB)
{
    __shared__ char lds[32768];
    char* As = lds;           // [128][128B] f16, byte = row*128 + (col2 ^ ((row&7)<<4))
    char* Bs = lds + 16384;   // 128B rows: (row&7)<<4 <= 112 < 128, bijective OK

    const int t = threadIdx.x;
    const int lane = t & 63;
    const int w = t >> 6;
    const int chunk = gridDim.x >> 3;                      // gridDim.x % 8 == 0
    const int bsw = (blockIdx.x & 7) * chunk + (blockIdx.x >> 3);
    const int m0 = (bsw / NB) * 128;
    const int n0 = (bsw % NB) * 128;
    const int wm = (w >> 1) * 64;
    const int wn = (w & 1) * 64;
    const int NK = Kdim >> 6;

    f32x4 acc[4][4];
#pragma unroll
    for (int i = 0; i < 4; ++i)
#pragma unroll
        for (int j = 0; j < 4; ++j) acc[i][j] = (f32x4){0.f, 0.f, 0.f, 0.f};

    float4 a32[8];
    int4   a16[4];
    int4   breg[4];

    auto loadA = [&](int kt) {
        if (VAR == 0) {
            const float* A = (const float*)Ap;
#pragma unroll
            for (int i = 0; i < 8; ++i) {
                const int cid = t + i * 256, row = cid >> 4, cir = cid & 15;
                a32[i] = *(const float4*)&A[(long)(m0 + row) * Kdim + kt * 64 + cir * 4];
            }
        } else {
            const f16* A = (const f16*)Ap;
#pragma unroll
            for (int i = 0; i < 4; ++i) {
                const int cid = t + i * 256, row = cid >> 3, cir = cid & 7;
                a16[i] = *(const int4*)&A[(long)(m0 + row) * Kdim + kt * 64 + cir * 8];
            }
        }
#pragma unroll
        for (int i = 0; i < 4; ++i) {
            const int cid = t + i * 256, row = cid >> 3, cir = cid & 7;
            breg[i] = *(const int4*)&Bt[(long)(n0 + row) * Kdim + kt * 64 + cir * 8];
        }
    };
    auto writeLDS = [&]() {
        if (VAR == 0) {
#pragma unroll
            for (int i = 0; i < 8; ++i) {
                const int cid = t + i * 256, row = cid >> 4, cir = cid & 15;
                f16x4 v = {(f16)a32[i].x, (f16)a32[i].y, (f16)a32[i].z, (f16)a32[i].w};
                *(f16x4*)(As + row * 128 + ((cir * 8) ^ ((row & 7) << 4))) = v;
            }
        } else {
#pragma unroll
            for (int i = 0; i < 4; ++i) {
                const int cid = t + i * 256, row = cid >> 3, cir = cid & 7;
                *(int4*)(As + row * 128 + ((cir * 16) ^ ((row & 7) << 4))) = a16[i];
            }
        }
#pragma unroll
        for (int i = 0; i < 4; ++i) {
            const int cid = t + i * 256, row = cid >> 3, cir = cid & 7;
            *(int4*)(Bs + row * 128 + ((cir * 16) ^ ((row & 7) << 4))) = breg[i];
        }
    };

    loadA(0);
    writeLDS();
    __syncthreads();

    for (int kt = 0; kt < NK; ++kt) {
        if (kt + 1 < NK) loadA(kt + 1);
#pragma unroll
        for (int ks = 0; ks < 2; ++ks) {
            f16x8 af[4], bf[4];
            const int kb = (ks * 32 + ((lane >> 4) * 8)) * 2;
#pragma unroll
            for (int mb = 0; mb < 4; ++mb) {
                const int row = wm + mb * 16 + (lane & 15);
                af[mb] = *(const f16x8*)(As + row * 128 + (kb ^ ((row & 7) << 4)));
            }
#pragma unroll
            for (int nb = 0; nb < 4; ++nb) {
                const int row = wn + nb * 16 + (lane & 15);
                bf[nb] = *(const f16x8*)(Bs + row * 128 + (kb ^ ((row & 7) << 4)));
            }
#pragma unroll
            for (int mb = 0; mb < 4; ++mb)
#pragma unroll
                for (int nb = 0; nb < 4; ++nb)
                    acc[mb][nb] = MFMA16(af[mb], bf[nb], acc[mb][nb]);
        }
        __syncthreads();
        if (kt + 1 < NK) { writeLDS(); __syncthreads(); }
    }

#pragma unroll
    for (int nb = 0; nb < 4; ++nb) {
        const int col = n0 + wn + nb * 16 + (lane & 15);
        const float bv = bias[col];
        const float sc = (VAR == 0 && col < HID) ? SCALE : 1.0f;
#pragma unroll
        for (int mb = 0; mb < 4; ++mb)
#pragma unroll
            for (int j = 0; j < 4; ++j) {
                const int row = m0 + wm + mb * 16 + (lane >> 4) * 4 + j;
                const float v = (acc[mb][nb][j] + bv) * sc;
                if (VAR == 0) ((f16*)Cp)[(long)row * Ndim + col] = (f16)v;
                else          ((float*)Cp)[(long)row * Ndim + col] = v;
            }
    }
}

// ---------------------------------------------------------------------------
// Flash attention, f16 MFMA, within-block KV-split.
// qkv rows: [q*0.125 (256) | k (256) | v (256)] f16.
// Block: 256 thr (4 waves). wave w: rg=w&1 (q-row group of 16), kh=w>>1
// (kv half). QM=32 q-rows/block, KT=32 kv/tile.
// SWIZZLE RULE (bug fixed r7): XOR stripe must stay inside the row.
//   512B rows (Ks): sw=(row&15)<<4 (<=240<512, bijective).
//   64B rows (Vt,P): sw=(row&3)<<4  (<=48<64, bijective).  (row&7)<<4 ESCAPED
//   the 64B row: rows 7&8 collided -> P/V corruption -> absmax 2.7e-2.
// ---------------------------------------------------------------------------
#define QM 32
#define KT 32
#define KVHALF 1152
#define NT (KVHALF / KT)   // 36

__global__ __launch_bounds__(256, 2) void attn_mfma(
    const f16* __restrict__ qkv, f16* __restrict__ attno)
{
    __shared__ char lds[69888];
    // [0, 32K): Ks, half kh at kh*16384: [32 rows][512B], swz ^((row&15)<<4)
    // [32K, 64K): Vt, half kh at 32768+kh*16384: [256 d][64B], swz ^((d&3)<<4)
    // [64K, 68K): P, wave w at 65536+w*1024: [16 rows][64B], swz ^((row&3)<<4)
    // epilogue reuse: [0,32K) o-f32 of kh=1 waves ([rg] 16KB: [16 rows][256 d])
    //                [69632+rg*128): m,l pairs (16 rows x 2 f32)

    const int t    = threadIdx.x;
    const int lane = t & 63;
    const int w    = t >> 6;
    const int rg   = w & 1;        // q-row group
    const int kh   = w >> 1;       // kv half
    const int tt   = t & 127;      // thread index within kv-half (2 waves)
    const int b    = blockIdx.x & 7;
    const int q0   = (blockIdx.x >> 3) * QM;
    const long base = (long)b * NN;
    const int kv0  = kh * KVHALF;

    char* KsH = lds + kh * 16384;
    char* VtH = lds + 32768 + kh * 16384;
    char* PwW = lds + 65536 + w * 1024;

    // ---- Q fragments in registers (wave's 16 rows, full D=256) ----
    const int qrow = q0 + rg * 16 + (lane & 15);
    f16x8 qf[8];
    {
        const f16* qsrc = qkv + (base + qrow) * QKV3 + ((lane >> 4) * 8);
#pragma unroll
        for (int ks = 0; ks < 8; ++ks)
            qf[ks] = *(const f16x8*)(qsrc + ks * 32);
    }

    f32x4 o[16];
#pragma unroll
    for (int i = 0; i < 16; ++i) o[i] = (f32x4){0.f, 0.f, 0.f, 0.f};
    float m[4], lsum[4];
#pragma unroll
    for (int j = 0; j < 4; ++j) { m[j] = -1e30f; lsum[j] = 0.f; }

    // staging maps (128 threads per half)
    const int vquad = tt & 7;        // 8 quads x 4 kv rows = 32 rows
    const int vdg   = (tt >> 3) * 16; // 16 d-groups x 16 d = 256

    int4  kreg[8];
    f16x8 vreg[8];
    auto loadTile = [&](int tile) {
        const long kbase = base + kv0 + tile * KT;
#pragma unroll
        for (int i = 0; i < 8; ++i) {
            const int cid = tt + i * 128, row = cid >> 5, cir = cid & 31;
            kreg[i] = *(const int4*)(qkv + (kbase + row) * QKV3 + 256 + cir * 8);
        }
#pragma unroll
        for (int r = 0; r < 4; ++r) {
            const f16* vs = qkv + (kbase + vquad * 4 + r) * QKV3 + 512 + vdg;
            vreg[r * 2]     = *(const f16x8*)(vs);
            vreg[r * 2 + 1] = *(const f16x8*)(vs + 8);
        }
    };
    auto writeTile = [&]() {
#pragma unroll
        for (int i = 0; i < 8; ++i) {
            const int cid = tt + i * 128, row = cid >> 5, cir = cid & 31;
            *(int4*)(KsH + row * 512 + ((cir * 16) ^ ((row & 15) << 4))) = kreg[i];
        }
#pragma unroll
        for (int i = 0; i < 16; ++i) {
            const int d = vdg + i;
            f16x4 wv;
#pragma unroll
            for (int r = 0; r < 4; ++r)
                wv[r] = (i < 8) ? vreg[r * 2][i] : vreg[r * 2 + 1][i - 8];
            *(f16x4*)(VtH + d * 64 + ((vquad * 8) ^ ((d & 3) << 4))) = wv;
        }
    };

    loadTile(0);

    for (int tile = 0; tile < NT; ++tile) {
        __syncthreads();            // previous tile's LDS reads complete
        writeTile();
        __syncthreads();            // staging visible
        if (tile + 1 < NT) loadTile(tile + 1);   // prefetch (hides under compute)

        // ---- S = Q @ K^T : 16 q x 32 kv ----
        f32x4 s[2];
        s[0] = (f32x4){0.f, 0.f, 0.f, 0.f};
        s[1] = (f32x4){0.f, 0.f, 0.f, 0.f};
        __builtin_amdgcn_s_setprio(1);
#pragma unroll
        for (int ks = 0; ks < 8; ++ks) {
            const int kb = (ks * 32 + (lane >> 4) * 8) * 2;
#pragma unroll
            for (int nb = 0; nb < 2; ++nb) {
                const int row = nb * 16 + (lane & 15);
                f16x8 kf = *(const f16x8*)(KsH + row * 512 + (kb ^ ((row & 15) << 4)));
                s[nb] = MFMA16(qf[ks], kf, s[nb]);
            }
        }
        __builtin_amdgcn_s_setprio(0);

        // ---- online softmax (row r = (lane>>4)*4 + j lives in 16-lane group) ----
        float f[4];
#pragma unroll
        for (int j = 0; j < 4; ++j) {
            float rmax = fmaxf(s[0][j], s[1][j]);
            rmax = fmaxf(rmax, __shfl_xor(rmax, 1));
            rmax = fmaxf(rmax, __shfl_xor(rmax, 2));
            rmax = fmaxf(rmax, __shfl_xor(rmax, 4));
            rmax = fmaxf(rmax, __shfl_xor(rmax, 8));
            const float mnew = fmaxf(m[j], rmax);
            f[j] = __expf(m[j] - mnew);
            const float p0 = __expf(s[0][j] - mnew);
            const float p1 = __expf(s[1][j] - mnew);
            float ps = p0 + p1;
            ps += __shfl_xor(ps, 1);
            ps += __shfl_xor(ps, 2);
            ps += __shfl_xor(ps, 4);
            ps += __shfl_xor(ps, 8);
            lsum[j] = lsum[j] * f[j] + ps;
            m[j] = mnew;
            const int prow = (lane >> 4) * 4 + j;
            char* pr = PwW + prow * 64;
            const int cb = (lane & 15) * 2;
            const int sw = (prow & 3) << 4;
            *(f16*)(pr + ((cb +  0) ^ sw)) = (f16)p0;
            *(f16*)(pr + ((cb + 32) ^ sw)) = (f16)p1;
        }
#pragma unroll
        for (int nb2 = 0; nb2 < 16; ++nb2)
#pragma unroll
            for (int j = 0; j < 4; ++j) o[nb2][j] *= f[j];

        asm volatile("s_waitcnt lgkmcnt(0)" ::: "memory");
        __builtin_amdgcn_sched_barrier(0);

        // ---- O += P @ V (single k-step: KT=32) ----
        {
            const int prow = lane & 15;
            const int kb = (lane >> 4) * 16;
            f16x8 pa = *(const f16x8*)(PwW + prow * 64 + (kb ^ ((prow & 3) << 4)));
            __builtin_amdgcn_s_setprio(1);
#pragma unroll
            for (int nb2 = 0; nb2 < 16; ++nb2) {
                const int d = nb2 * 16 + (lane & 15);
                f16x8 vb = *(const f16x8*)(VtH + d * 64 + (kb ^ ((d & 3) << 4)));
                o[nb2] = MFMA16(pa, vb, o[nb2]);
            }
            __builtin_amdgcn_s_setprio(0);
        }
    }

    // ---- merge kv-halves through LDS ----
    __syncthreads();
    if (kh == 1) {
        float* oL = (float*)(lds + rg * 16384);
#pragma unroll
        for (int nb2 = 0; nb2 < 16; ++nb2)
#pragma unroll
            for (int j = 0; j < 4; ++j)
                oL[((lane >> 4) * 4 + j) * 256 + nb2 * 16 + (lane & 15)] = o[nb2][j];
        if ((lane & 15) == 0) {
            float* ml = (float*)(lds + 69632 + rg * 128);
#pragma unroll
            for (int j = 0; j < 4; ++j) {
                const int row = (lane >> 4) * 4 + j;
                ml[row * 2]     = m[j];
                ml[row * 2 + 1] = lsum[j];
            }
        }
    }
    __syncthreads();
    if (kh == 0) {
        const float* oL = (const float*)(lds + rg * 16384);
        const float* ml = (const float*)(lds + 69632 + rg * 128);
#pragma unroll
        for (int j = 0; j < 4; ++j) {
            const int row = (lane >> 4) * 4 + j;
            const float m1 = ml[row * 2];
            const float l1 = ml[row * 2 + 1];
            const float M  = fmaxf(m[j], m1);
            const float e0 = __expf(m[j] - M);
            const float e1 = __expf(m1 - M);
            const float inv = 1.f / (lsum[j] * e0 + l1 * e1);
#pragma unroll
            for (int nb2 = 0; nb2 < 16; ++nb2) {
                const int col = nb2 * 16 + (lane & 15);
                const float v = (o[nb2][j] * e0 + oL[row * 256 + col] * e1) * inv;
                attno[(base + q0 + rg * 16 + row) * HID + col] = (f16)v;
            }
        }
    }
}

// ---------------------------------------------------------------------------
extern "C" void kernel_launch(void* const* d_in, const int* in_sizes, int n_in,
                              void* d_out, int out_size, void* d_ws, size_t ws_size,
                              hipStream_t stream)
{
    (void)in_sizes; (void)n_in; (void)out_size; (void)ws_size;
    const float* x  = (const float*)d_in[0];
    const float* W1 = (const float*)d_in[1];
    const float* b1 = (const float*)d_in[2];
    const float* W2 = (const float*)d_in[3];
    const float* b2 = (const float*)d_in[4];
    float* out = (float*)d_out;

    char* ws = (char*)d_ws;
    f16* W1t   = (f16*)ws;                               // 768*512  f16 = 768 KB
    f16* W2t   = (f16*)(ws + 786432);                    // 256*256  f16 = 128 KB
    f16* qkv   = (f16*)(ws + 786432 + 131072);           // 18432*768 f16 = 27 MB
    f16* attno = (f16*)(ws + 786432 + 131072 + 28311552);// 18432*256 f16 = 9 MB

    transpose_f32_to_f16<<<dim3(QKV3 / 32, CIN / 32), 256, 0, stream>>>(W1, W1t, CIN, QKV3);
    transpose_f32_to_f16<<<dim3(HID / 32, HID / 32), 256, 0, stream>>>(W2, W2t, HID, HID);
    // qkv = x @ W1 + b1 (f16 out, q pre-scaled)
    gemm_mfma<0><<<864, 256, 0, stream>>>(x, W1t, b1, qkv, CIN, QKV3, 6);
    // flash attention (within-block kv-split)
    attn_mfma<<<576, 256, 0, stream>>>(qkv, attno);
    // out = attno @ W2 + b2 (f32 out)
    gemm_mfma<1><<<288, 256, 0, stream>>>(attno, W2t, b2, out, HID, HID, 2);
}